// Round 6
// baseline (131.780 us; speedup 1.0000x reference)
//
#include <hip/hip_runtime.h>

// segment_sum via fixed-stride bucketing + gather, exact overflow fold.
// E = 1M edges, D = 64 f32 features, N = 100K nodes, ws ~1GB.
// R5: cleanup merged into gather (ovf_cnt==0 fast path), 8-deep unroll with
// int4 edge-id broadcasts, int4 tgt loads in scatter. No NT hints (R3 lesson).
//
// ws ints: cursor[N] | pad | ovf[2*OVF_CAP] (16B-aligned) | bucket[N*CAP]

typedef float f4 __attribute__((ext_vector_type(4)));

#define FEAT 64
#define CAP 32            // one 128B line per node row (avg deg 10)
#define OVF_CAP (1 << 20)

__global__ void __launch_bounds__(256)
scatter_kernel(const int4* __restrict__ tgt4, int* __restrict__ cursor,
               int* __restrict__ bucket, int* __restrict__ ovf_cnt,
               int* __restrict__ ovf, int E) {
    int i = blockIdx.x * 256 + threadIdx.x;
    int base = i * 4;
    if (base >= E) return;
    int4 t4 = tgt4[i];
    int t[4] = {t4.x, t4.y, t4.z, t4.w};
#pragma unroll
    for (int k = 0; k < 4; ++k) {
        if (base + k < E) {
            int pos = atomicAdd(&cursor[t[k]], 1);
            if (pos < CAP) {
                bucket[t[k] * CAP + pos] = base + k;
            } else {                       // exact fallback, expected never
                int q = atomicAdd(ovf_cnt, 1);
                if (q < OVF_CAP) { ovf[2 * q] = t[k]; ovf[2 * q + 1] = base + k; }
            }
        }
    }
}

// 16-lane group per node; lane = float4 slot; up to 8 rows in flight per group
__global__ void __launch_bounds__(256)
gather_kernel(const f4* __restrict__ mj4, const int* __restrict__ cursor,
              const int* __restrict__ bucket, const int* __restrict__ ovf_cnt,
              const int* __restrict__ ovf, f4* __restrict__ out4, int N) {
    int gid = (blockIdx.x * 256 + threadIdx.x) >> 4;
    int l = threadIdx.x & 15;
    if (gid >= N) return;
    int deg = cursor[gid];
    if (deg > CAP) deg = CAP;
    const int* row = bucket + gid * CAP;          // one 128B line
    const int4* row4 = (const int4*)row;          // 16B-aligned (see layout)
    f4 acc = {0.f, 0.f, 0.f, 0.f};
    int j = 0;
    for (; j + 7 < deg; j += 8) {
        int4 ea = row4[j >> 2];
        int4 eb = row4[(j >> 2) + 1];
        f4 v0 = mj4[(size_t)ea.x * 16 + l];
        f4 v1 = mj4[(size_t)ea.y * 16 + l];
        f4 v2 = mj4[(size_t)ea.z * 16 + l];
        f4 v3 = mj4[(size_t)ea.w * 16 + l];
        f4 v4 = mj4[(size_t)eb.x * 16 + l];
        f4 v5 = mj4[(size_t)eb.y * 16 + l];
        f4 v6 = mj4[(size_t)eb.z * 16 + l];
        f4 v7 = mj4[(size_t)eb.w * 16 + l];
        acc += ((v0 + v1) + (v2 + v3)) + ((v4 + v5) + (v6 + v7));
    }
    for (; j + 3 < deg; j += 4) {
        int4 ea = row4[j >> 2];
        f4 v0 = mj4[(size_t)ea.x * 16 + l];
        f4 v1 = mj4[(size_t)ea.y * 16 + l];
        f4 v2 = mj4[(size_t)ea.z * 16 + l];
        f4 v3 = mj4[(size_t)ea.w * 16 + l];
        acc += (v0 + v1) + (v2 + v3);
    }
    for (; j < deg; ++j) {
        acc += mj4[(size_t)row[j] * 16 + l];
    }
    // exact overflow fold; ovf_cnt==0 in practice -> one cached scalar load
    int n = *ovf_cnt;
    if (n > 0) {
        if (n > OVF_CAP) n = OVF_CAP;
        for (int k = 0; k < n; ++k) {
            if (ovf[2 * k] == gid) acc += mj4[(size_t)ovf[2 * k + 1] * 16 + l];
        }
    }
    out4[(size_t)gid * 16 + l] = acc;
}

extern "C" void kernel_launch(void* const* d_in, const int* in_sizes, int n_in,
                              void* d_out, int out_size, void* d_ws, size_t ws_size,
                              hipStream_t stream) {
    const float* mj = (const float*)d_in[0];
    const int* edge_index = (const int*)d_in[1];  // [2, E] int32 row-major
    int E = in_sizes[1] / 2;
    const int* tgt = edge_index + E;              // row 1 = targets
    int N = out_size / FEAT;                      // 100,000

    int* cursor  = (int*)d_ws;                    // N ints
    int* ovf_cnt = cursor + N;                    // 1 (+3 pad)
    int* ovf     = cursor + N + 4;                // 2*OVF_CAP, 16B-aligned
    int* bucket  = ovf + 2 * OVF_CAP;             // N*CAP ints, 16B-aligned

    hipMemsetAsync(cursor, 0, (size_t)(N + 4) * sizeof(int), stream);

    int e4 = (E + 3) / 4;
    int eblk = (e4 + 255) / 256;
    scatter_kernel<<<eblk, 256, 0, stream>>>(
        (const int4*)tgt, cursor, bucket, ovf_cnt, ovf, E);

    int gblk = (N * 16 + 255) / 256;
    gather_kernel<<<gblk, 256, 0, stream>>>(
        (const f4*)mj, cursor, bucket, ovf_cnt, ovf, (f4*)d_out, N);
}